// Round 9
// baseline (273.827 us; speedup 1.0000x reference)
//
#include <hip/hip_runtime.h>

constexpr int NN = 50000;   // nodes
constexpr int NE = 600000;  // edges
constexpr int D  = 128;     // features
constexpr int NR = 8;       // relations
constexpr int NSEG = NR * NN;        // 400000 (rel, dst) segments, seg = r*NN + dst

constexpr int SCAN_ELEMS = 1024;
constexpr int NBLK2 = (NSEG + SCAN_ELEMS - 1) / SCAN_ELEMS;   // 391

typedef unsigned int   u32;
typedef unsigned short u16;
typedef float  f32x4 __attribute__((ext_vector_type(4)));
typedef short  s16x8 __attribute__((ext_vector_type(8)));

__device__ __forceinline__ u16 f2bf(float f) {
    u32 u = __float_as_uint(f);
    u32 r = (u + 0x7fffu + ((u >> 16) & 1u)) >> 16;   // RNE
    return (u16)r;
}

__device__ __forceinline__ void async_cp16(const void* g, void* l) {
    __builtin_amdgcn_global_load_lds(
        (const __attribute__((address_space(1))) u32*)g,
        (__attribute__((address_space(3))) u32*)l, 16, 0, 0);
}

// ---------------- fused prep: count + convert_x + transpose_w ------------
__global__ __launch_bounds__(256) void prep_all(const float* __restrict__ x,
                                                const float* __restrict__ weight,
                                                const float* __restrict__ root,
                                                const int* __restrict__ dst,
                                                const int* __restrict__ et,
                                                u16* __restrict__ xb,
                                                u16* __restrict__ wt,
                                                u16* __restrict__ rt,
                                                int* __restrict__ cnt2) {
    const int NX4 = NN * D / 4;                 // 1.6M
    const int NW  = (NR + 1) * D * D;           // 147456
    int gid = blockIdx.x * 256 + threadIdx.x;
    if (gid < NX4) {
        int i = gid * 4;
        float4 v = *(const float4*)(x + i);
        ushort4 o;
        o.x = f2bf(v.x); o.y = f2bf(v.y); o.z = f2bf(v.z); o.w = f2bf(v.w);
        *(ushort4*)(xb + i) = o;
        return;
    }
    int g = gid - NX4;
    if (g < NW) {
        int p = g >> 14;          // plane 0..8
        int idx = g & 16383;      // c*128 + k
        int c = idx >> 7, k = idx & 127;
        float v = (p < NR) ? weight[(size_t)p * D * D + k * D + c] : root[k * D + c];
        u16* dp = (p < NR) ? (wt + (size_t)p * D * D) : rt;
        dp[idx] = f2bf(v);
        return;
    }
    int e = g - NW;
    if (e < NE) atomicAdd(&cnt2[et[e] * NN + dst[e]], 1);
}

// ---------------- scans: exclusive scan of cnt2 -> offs2 -----------------
__global__ __launch_bounds__(256) void scan1(const int* __restrict__ cnt,
                                             int* __restrict__ offs,
                                             int* __restrict__ bsums) {
    __shared__ int lds[256];
    int t = threadIdx.x;
    int base = blockIdx.x * SCAN_ELEMS + t * 4;
    int v0 = (base + 0 < NSEG) ? cnt[base + 0] : 0;
    int v1 = (base + 1 < NSEG) ? cnt[base + 1] : 0;
    int v2 = (base + 2 < NSEG) ? cnt[base + 2] : 0;
    int v3 = (base + 3 < NSEG) ? cnt[base + 3] : 0;
    int s = v0 + v1 + v2 + v3;
    lds[t] = s;
    __syncthreads();
    int val = s;
    for (int off = 1; off < 256; off <<= 1) {
        int tmp = (t >= off) ? lds[t - off] : 0;
        __syncthreads();
        val += tmp;
        lds[t] = val;
        __syncthreads();
    }
    int ex = val - s;
    if (base + 0 < NSEG) offs[base + 0] = ex;
    if (base + 1 < NSEG) offs[base + 1] = ex + v0;
    if (base + 2 < NSEG) offs[base + 2] = ex + v0 + v1;
    if (base + 3 < NSEG) offs[base + 3] = ex + v0 + v1 + v2;
    if (t == 255) bsums[blockIdx.x] = val;
}

__global__ __launch_bounds__(512) void scan2(int* __restrict__ bsums) {
    __shared__ int lds[512];
    int t = threadIdx.x;
    int v = (t < NBLK2) ? bsums[t] : 0;
    lds[t] = v;
    __syncthreads();
    int val = v;
    for (int off = 1; off < 512; off <<= 1) {
        int tmp = (t >= off) ? lds[t - off] : 0;
        __syncthreads();
        val += tmp;
        lds[t] = val;
        __syncthreads();
    }
    if (t < NBLK2) bsums[t] = val - v;
}

__global__ __launch_bounds__(256) void scan3(int* __restrict__ offs,
                                             int* __restrict__ cur,
                                             const int* __restrict__ bsums) {
    int i = blockIdx.x * 256 + threadIdx.x;
    if (i < NSEG) {
        int v = offs[i] + bsums[i >> 10];
        offs[i] = v;
        cur[i]  = v;
    }
    if (i == 0) offs[NSEG] = NE;
}

// ---------------- bin edges by (rel, dst) --------------------------------
__global__ __launch_bounds__(256) void fill_bins(const int* __restrict__ src,
                                                 const int* __restrict__ dst,
                                                 const int* __restrict__ et,
                                                 int* __restrict__ cur,
                                                 int* __restrict__ ebin) {
    int e = blockIdx.x * 256 + threadIdx.x;
    if (e >= NE) return;
    int d = dst[e];
    int idx = atomicAdd(&cur[et[e] * NN + d], 1);
    ebin[idx] = (int)(((u32)d << 16) | (u32)src[e]);   // both < 2^16
}

// ---------------- fused aggregate + MFMA GEMM ----------------------------
// Block = 128 nodes, 256 threads (4 waves, each 64x64 of the 128x128 out
// tile). For each of 9 K-planes: build the 128x128 bf16 A-tile in LDS
// (plane 0: copy xb rows; planes 1..8: boundary-flush mean-gather of that
// relation's contiguous edge stream), stage the 32KB B-plane via
// global_load_lds with XOR chunk swizzle, then 4 MFMA K-iters.
// A-tile rows padded to 136 u16 -> 2-way banks (free); B swizzle pos =
// chunk ^ (col&15) -> 2-way (free). The sums intermediate never exists.
__global__ __launch_bounds__(256) void fused_kernel(const u32* __restrict__ xw,
                                                    const u16* __restrict__ wt,
                                                    const u16* __restrict__ rt,
                                                    const int* __restrict__ offs,
                                                    const int* __restrict__ ebin,
                                                    const float* __restrict__ bias,
                                                    float* __restrict__ out) {
    __shared__ u16 As[128 * 136];   // 34.8 KB, padded
    __shared__ u16 Bs[128 * 128];   // 32 KB, chunk-swizzled

    const int tid  = threadIdx.x;
    const int wave = tid >> 6;
    const int lane = tid & 63;
    const int m0   = blockIdx.x * 128;
    const int wm   = (wave & 1) * 64;
    const int wn   = (wave >> 1) * 64;
    const int fr   = lane & 15;
    const int fq   = lane >> 4;
    u32* Asw = (u32*)As;

    int node_lo = m0 + wave * 32; if (node_lo > NN) node_lo = NN;
    int node_hi = node_lo + 32;   if (node_hi > NN) node_hi = NN;

    f32x4 acc[4][4];
#pragma unroll
    for (int i = 0; i < 4; ++i)
#pragma unroll
        for (int j = 0; j < 4; ++j) acc[i][j] = (f32x4){0.f, 0.f, 0.f, 0.f};

    for (int p = 0; p <= NR; ++p) {
        // ---- stage B plane (32 KB), XOR chunk swizzle ----
        const u16* Bp = (p == 0) ? rt : wt + (size_t)(p - 1) * D * D;
#pragma unroll
        for (int j = 0; j < 8; ++j) {
            int gcid = j * 256 + tid;            // chunk id 0..2047
            int col  = gcid >> 4;
            int gch  = (gcid & 15) ^ (col & 15); // source chunk (swizzle)
            async_cp16(Bp + col * D + gch * 8,
                       (char*)Bs + (size_t)(j * 256 + wave * 64) * 16);
        }

        // ---- fill A tile ----
        if (p == 0) {
            for (int n = node_lo; n < node_hi; n += 8) {
                u32 vv[8];
                int lim = node_hi - n; if (lim > 8) lim = 8;
                for (int j = 0; j < lim; ++j) vv[j] = xw[(size_t)(n + j) * 64 + lane];
                for (int j = 0; j < lim; ++j) Asw[(n + j - m0) * 68 + lane] = vv[j];
            }
        } else {
            const int r = p - 1;
            const int lo = __builtin_amdgcn_readfirstlane(offs[r * NN + node_lo]);
            const int c  = __builtin_amdgcn_readfirstlane(offs[r * NN + node_hi]) - lo;
            float a0 = 0.f, a1 = 0.f;
            int cnt_cur = 0, n_cur = node_lo;

            int q0 = 0, q1 = 0, q2 = 0, q3 = 0, q4 = 0, q5 = 0, q6 = 0, q7 = 0;
            u32 v0 = 0, v1 = 0, v2 = 0, v3 = 0, v4 = 0, v5 = 0, v6 = 0, v7 = 0;

#define REFILL(Q, V, IDX)                                                   \
    if ((IDX) < c) {                                                        \
        Q = __builtin_amdgcn_readfirstlane(ebin[lo + (IDX)]);               \
        V = xw[(size_t)((u32)Q & 0xffffu) * 64 + lane];                     \
    }
#define FLUSH()                                                             \
    {                                                                       \
        float inv_ = 1.0f / (float)(cnt_cur > 0 ? cnt_cur : 1);             \
        u32 lo16_ = f2bf(a0 * inv_);                                        \
        u32 hi16_ = f2bf(a1 * inv_);                                        \
        Asw[(n_cur - m0) * 68 + lane] = lo16_ | (hi16_ << 16);              \
        a0 = 0.f; a1 = 0.f; cnt_cur = 0; ++n_cur;                           \
    }
#define CONSUME(Q, V)                                                       \
    {                                                                       \
        int dn_ = (int)((u32)(Q) >> 16);                                    \
        while (n_cur < dn_) FLUSH()                                         \
        a0 += __uint_as_float((V) << 16);                                   \
        a1 += __uint_as_float((V) & 0xffff0000u);                           \
        ++cnt_cur;                                                          \
    }
            REFILL(q0, v0, 0) REFILL(q1, v1, 1) REFILL(q2, v2, 2) REFILL(q3, v3, 3)
            REFILL(q4, v4, 4) REFILL(q5, v5, 5) REFILL(q6, v6, 6) REFILL(q7, v7, 7)
            int e = 0;
            for (; e + 8 <= c; e += 8) {
                CONSUME(q0, v0) REFILL(q0, v0, e + 8)
                CONSUME(q1, v1) REFILL(q1, v1, e + 9)
                CONSUME(q2, v2) REFILL(q2, v2, e + 10)
                CONSUME(q3, v3) REFILL(q3, v3, e + 11)
                CONSUME(q4, v4) REFILL(q4, v4, e + 12)
                CONSUME(q5, v5) REFILL(q5, v5, e + 13)
                CONSUME(q6, v6) REFILL(q6, v6, e + 14)
                CONSUME(q7, v7) REFILL(q7, v7, e + 15)
            }
            if (e + 0 < c) CONSUME(q0, v0)
            if (e + 1 < c) CONSUME(q1, v1)
            if (e + 2 < c) CONSUME(q2, v2)
            if (e + 3 < c) CONSUME(q3, v3)
            if (e + 4 < c) CONSUME(q4, v4)
            if (e + 5 < c) CONSUME(q5, v5)
            if (e + 6 < c) CONSUME(q6, v6)
            if (e + 7 < c) CONSUME(q7, v7)
            while (n_cur < node_hi) FLUSH()
#undef REFILL
#undef FLUSH
#undef CONSUME
        }

        __syncthreads();   // A tile + B plane (vmcnt drained) visible

        // ---- 4 MFMA K-iters over this plane ----
#pragma unroll
        for (int kk = 0; kk < 4; ++kk) {
            const int ch = kk * 4 + fq;     // 16B chunk index within plane K
            s16x8 af[4], bf[4];
#pragma unroll
            for (int mt = 0; mt < 4; ++mt)
                af[mt] = *(const s16x8*)&As[(wm + mt * 16 + fr) * 136 + ch * 8];
#pragma unroll
            for (int nt = 0; nt < 4; ++nt) {
                int col = wn + nt * 16 + fr;
                int pos = ch ^ (col & 15);
                bf[nt] = *(const s16x8*)&Bs[col * 128 + pos * 8];
            }
#pragma unroll
            for (int mt = 0; mt < 4; ++mt)
#pragma unroll
                for (int nt = 0; nt < 4; ++nt)
                    acc[mt][nt] = __builtin_amdgcn_mfma_f32_16x16x32_bf16(
                        af[mt], bf[nt], acc[mt][nt], 0, 0, 0);
        }
        __syncthreads();   // done reading before next plane overwrites
    }

    // ---- epilogue: bias + relu, nontemporal stores ----
    const int cl = lane & 15;
    const int rq = (lane >> 4) * 4;
#pragma unroll
    for (int nt = 0; nt < 4; ++nt) {
        int col = wn + nt * 16 + cl;
        float bv = bias[col];
#pragma unroll
        for (int mt = 0; mt < 4; ++mt) {
#pragma unroll
            for (int reg = 0; reg < 4; ++reg) {
                int n = m0 + wm + mt * 16 + rq + reg;
                if (n < NN) {
                    float v = fmaxf(acc[mt][nt][reg] + bv, 0.0f);
                    __builtin_nontemporal_store(v, &out[(size_t)n * D + col]);
                }
            }
        }
    }
}

extern "C" void kernel_launch(void* const* d_in, const int* in_sizes, int n_in,
                              void* d_out, int out_size, void* d_ws, size_t ws_size,
                              hipStream_t stream) {
    const float* x      = (const float*)d_in[0];
    const int*   ei     = (const int*)d_in[1];
    const int*   et     = (const int*)d_in[2];
    const float* weight = (const float*)d_in[3];
    const float* root   = (const float*)d_in[4];
    const float* bias   = (const float*)d_in[5];
    float* out = (float*)d_out;
    const int* srcv = ei;
    const int* dstv = ei + NE;

    // ws: ints [cnt2 NSEG][cur2 NSEG][offs2 NSEG+1][bsums 512][ebin NE],
    // then u16 [xb NN*D][wt NR*D*D][rt D*D]   (~20 MB)
    int* cnt2  = (int*)d_ws;
    int* cur2  = cnt2 + NSEG;
    int* offs2 = cur2 + NSEG;
    int* bsums = offs2 + NSEG + 1;
    int* ebin  = bsums + 512;
    size_t fixed_b  = ((char*)(ebin + NE) - (char*)d_ws);
    size_t fixed_al = (fixed_b + 255) & ~(size_t)255;
    u16* xb = (u16*)((char*)d_ws + fixed_al);
    u16* wt = xb + (size_t)NN * D;
    u16* rt = wt + (size_t)NR * D * D;

    hipMemsetAsync(cnt2, 0, NSEG * sizeof(int), stream);

    const int PREP = NN * D / 4 + (NR + 1) * D * D + NE;
    prep_all<<<(PREP + 255) / 256, 256, 0, stream>>>(x, weight, root, dstv, et,
                                                     xb, wt, rt, cnt2);

    scan1<<<NBLK2, 256, 0, stream>>>(cnt2, offs2, bsums);
    scan2<<<1, 512, 0, stream>>>(bsums);
    scan3<<<(NSEG + 256) / 256, 256, 0, stream>>>(offs2, cur2, bsums);
    fill_bins<<<(NE + 255) / 256, 256, 0, stream>>>(srcv, dstv, et, cur2, ebin);

    fused_kernel<<<(NN + 127) / 128, 256, 0, stream>>>((const u32*)xb, wt, rt,
                                                       offs2, ebin, bias, out);
}

// Round 11
// 242.476 us; speedup vs baseline: 1.1293x; 1.1293x over previous
//
#include <hip/hip_runtime.h>

constexpr int NN = 50000;   // nodes
constexpr int NE = 600000;  // edges
constexpr int D  = 128;     // features
constexpr int NR = 8;       // relations
constexpr int NSEG = NN * NR;        // 400000 (dst, rel) segments

constexpr int SCAN_ELEMS = 1024;
constexpr int NBLK2 = (NSEG + SCAN_ELEMS - 1) / SCAN_ELEMS;   // 391

typedef unsigned int   u32;
typedef unsigned short u16;
typedef float  f32x4 __attribute__((ext_vector_type(4)));
typedef short  s16x8 __attribute__((ext_vector_type(8)));

__device__ __forceinline__ u16 f2bf(float f) {
    u32 u = __float_as_uint(f);
    u32 r = (u + 0x7fffu + ((u >> 16) & 1u)) >> 16;   // RNE
    return (u16)r;
}

// ---------------- fused prep: count + convert_x + pack W -----------------
// bpk layout (MFMA B-fragment order): PLANE 0 = root, plane r+1 = weight[r]
// (matches the GEMM's A-plane convention: plane 0 = x, plane p = mean[p-1]).
// Within a plane: k-chunk ch = k>>3 (16 per plane), col c: the 16B chunk at
// ((plane*16+ch)*128 + c)*8 + (k&7). A wave's B-fragment load (fr->col,
// fq->chunk) is then 4 contiguous 256B runs.
__global__ __launch_bounds__(256) void prep_all(const float* __restrict__ x,
                                                const float* __restrict__ weight,
                                                const float* __restrict__ root,
                                                const int* __restrict__ dst,
                                                const int* __restrict__ et,
                                                u16* __restrict__ xb,
                                                u16* __restrict__ bpk,
                                                int* __restrict__ cnt2) {
    const int NX4 = NN * D / 4;                 // 1.6M
    const int NW  = (NR + 1) * D * D;           // 147456
    int gid = blockIdx.x * 256 + threadIdx.x;
    if (gid < NX4) {
        int i = gid * 4;
        float4 v = *(const float4*)(x + i);
        ushort4 o;
        o.x = f2bf(v.x); o.y = f2bf(v.y); o.z = f2bf(v.z); o.w = f2bf(v.w);
        *(ushort4*)(xb + i) = o;
        return;
    }
    int g = gid - NX4;
    if (g < NW) {
        int p = g >> 14;          // source plane 0..8 (0..7 = weight, 8 = root)
        int idx = g & 16383;      // c*128 + k
        int c = idx >> 7, k = idx & 127;
        float v  = (p < NR) ? weight[(size_t)p * D * D + k * D + c] : root[k * D + c];
        int   dp = (p < NR) ? (p + 1) : 0;       // dest plane: root first
        bpk[(((size_t)dp * 16 + (k >> 3)) * 128 + c) * 8 + (k & 7)] = f2bf(v);
        return;
    }
    int e = g - NW;
    if (e < NE) atomicAdd(&cnt2[dst[e] * NR + et[e]], 1);
}

// ---------------- scans: exclusive scan of cnt2 -> offs2 -----------------
__global__ __launch_bounds__(256) void scan1(const int* __restrict__ cnt,
                                             int* __restrict__ offs,
                                             int* __restrict__ bsums) {
    __shared__ int lds[256];
    int t = threadIdx.x;
    int base = blockIdx.x * SCAN_ELEMS + t * 4;
    int v0 = (base + 0 < NSEG) ? cnt[base + 0] : 0;
    int v1 = (base + 1 < NSEG) ? cnt[base + 1] : 0;
    int v2 = (base + 2 < NSEG) ? cnt[base + 2] : 0;
    int v3 = (base + 3 < NSEG) ? cnt[base + 3] : 0;
    int s = v0 + v1 + v2 + v3;
    lds[t] = s;
    __syncthreads();
    int val = s;
    for (int off = 1; off < 256; off <<= 1) {
        int tmp = (t >= off) ? lds[t - off] : 0;
        __syncthreads();
        val += tmp;
        lds[t] = val;
        __syncthreads();
    }
    int ex = val - s;
    if (base + 0 < NSEG) offs[base + 0] = ex;
    if (base + 1 < NSEG) offs[base + 1] = ex + v0;
    if (base + 2 < NSEG) offs[base + 2] = ex + v0 + v1;
    if (base + 3 < NSEG) offs[base + 3] = ex + v0 + v1 + v2;
    if (t == 255) bsums[blockIdx.x] = val;
}

__global__ __launch_bounds__(512) void scan2(int* __restrict__ bsums) {
    __shared__ int lds[512];
    int t = threadIdx.x;
    int v = (t < NBLK2) ? bsums[t] : 0;
    lds[t] = v;
    __syncthreads();
    int val = v;
    for (int off = 1; off < 512; off <<= 1) {
        int tmp = (t >= off) ? lds[t - off] : 0;
        __syncthreads();
        val += tmp;
        lds[t] = val;
        __syncthreads();
    }
    if (t < NBLK2) bsums[t] = val - v;
}

__global__ __launch_bounds__(256) void scan3(int* __restrict__ offs,
                                             int* __restrict__ cur,
                                             const int* __restrict__ bsums) {
    int i = blockIdx.x * 256 + threadIdx.x;
    if (i < NSEG) {
        int v = offs[i] + bsums[i >> 10];
        offs[i] = v;
        cur[i]  = v;
    }
    if (i == 0) offs[NSEG] = NE;
}

// ---------------- bin edges by (dst, rel) --------------------------------
__global__ __launch_bounds__(256) void fill_bins(const int* __restrict__ src,
                                                 const int* __restrict__ dst,
                                                 const int* __restrict__ et,
                                                 int* __restrict__ cur,
                                                 int* __restrict__ ebin) {
    int e = blockIdx.x * 256 + threadIdx.x;
    if (e >= NE) return;
    int r = et[e];
    int idx = atomicAdd(&cur[dst[e] * NR + r], 1);
    ebin[idx] = (r << 16) | src[e];   // src < 50000 < 2^16
}

// ---------------- aggregation: relation-sorted, boundary-flush -----------
// One 64-lane wave per node, zero LDS. Edges arrive sorted by relation, so
// one running (lo,hi) accumulator pair suffices; a scalar flush at each
// relation boundary writes that relation's mean (zeros for empty segments)
// and the flush counter IS the segment count. Depth-8 gather pipeline.
__global__ __launch_bounds__(128) void aggregate_kernel(const u32* __restrict__ xw,
                                                        const int* __restrict__ offs2,
                                                        const int* __restrict__ ebin,
                                                        u32* __restrict__ sw) {
    const int lane = threadIdx.x & 63;
    const int n = blockIdx.x * 2 + (threadIdx.x >> 6);
    if (n >= NN) return;
    const int beg = __builtin_amdgcn_readfirstlane(offs2[n * NR]);
    const int c   = __builtin_amdgcn_readfirstlane(offs2[n * NR + NR]) - beg;

    float a0 = 0.f, a1 = 0.f;
    int r_cur = 0, cnt_cur = 0;

    int q0 = 0, q1 = 0, q2 = 0, q3 = 0, q4 = 0, q5 = 0, q6 = 0, q7 = 0;
    u32 v0 = 0, v1 = 0, v2 = 0, v3 = 0, v4 = 0, v5 = 0, v6 = 0, v7 = 0;

#define REFILL(Q, V, IDX)                                                   \
    if ((IDX) < c) {                                                        \
        Q = __builtin_amdgcn_readfirstlane(ebin[beg + (IDX)]);              \
        V = xw[(size_t)((u32)Q & 0xffffu) * 64 + lane];                     \
    }
#define FLUSH()                                                             \
    {                                                                       \
        float inv_ = 1.0f / (float)(cnt_cur > 0 ? cnt_cur : 1);             \
        u32 lo16_ = f2bf(a0 * inv_);                                        \
        u32 hi16_ = f2bf(a1 * inv_);                                        \
        sw[((size_t)r_cur * NN + n) * 64 + lane] = lo16_ | (hi16_ << 16);   \
        a0 = 0.f; a1 = 0.f; cnt_cur = 0; ++r_cur;                           \
    }
#define CONSUME(Q, V)                                                       \
    {                                                                       \
        int rj_ = (int)((u32)(Q) >> 16);                                    \
        while (r_cur < rj_) FLUSH()                                         \
        a0 += __uint_as_float((V) << 16);                                   \
        a1 += __uint_as_float((V) & 0xffff0000u);                           \
        ++cnt_cur;                                                          \
    }

    REFILL(q0, v0, 0) REFILL(q1, v1, 1) REFILL(q2, v2, 2) REFILL(q3, v3, 3)
    REFILL(q4, v4, 4) REFILL(q5, v5, 5) REFILL(q6, v6, 6) REFILL(q7, v7, 7)

    int e = 0;
    for (; e + 8 <= c; e += 8) {
        CONSUME(q0, v0) REFILL(q0, v0, e + 8)
        CONSUME(q1, v1) REFILL(q1, v1, e + 9)
        CONSUME(q2, v2) REFILL(q2, v2, e + 10)
        CONSUME(q3, v3) REFILL(q3, v3, e + 11)
        CONSUME(q4, v4) REFILL(q4, v4, e + 12)
        CONSUME(q5, v5) REFILL(q5, v5, e + 13)
        CONSUME(q6, v6) REFILL(q6, v6, e + 14)
        CONSUME(q7, v7) REFILL(q7, v7, e + 15)
    }
    if (e + 0 < c) CONSUME(q0, v0)
    if (e + 1 < c) CONSUME(q1, v1)
    if (e + 2 < c) CONSUME(q2, v2)
    if (e + 3 < c) CONSUME(q3, v3)
    if (e + 4 < c) CONSUME(q4, v4)
    if (e + 5 < c) CONSUME(q5, v5)
    if (e + 6 < c) CONSUME(q6, v6)
    if (e + 7 < c) CONSUME(q7, v7)

    while (r_cur < NR) FLUSH()
#undef REFILL
#undef FLUSH
#undef CONSUME
}

// ---------------- direct-load MFMA GEMM (no LDS, no barriers) ------------
// out[n][c] = relu( Σ_k A[n][k] * B[k][c] + bias[c] ), K = 1152.
// BM=64: 4 waves, wave w owns rows m0+16w..+15, all 128 cols (8 MFMA/kk).
// A fragments loaded per-lane straight from xb/sums (row fr, chunk fq);
// B fragments from bpk's fragment-order layout (4x256B coalesced, plane is
// L1/L2-resident and shared by all 782 blocks). A-plane 0 = x pairs with
// bpk plane 0 = root; A-plane p = mean[p-1] pairs with bpk plane p =
// weight[p-1]. Loads pipeline freely across k-chunks and planes.
__global__ __launch_bounds__(256) void mfma_gemm(const u16* __restrict__ xb,
                                                 const u16* __restrict__ sums,
                                                 const u16* __restrict__ bpk,
                                                 const float* __restrict__ bias,
                                                 float* __restrict__ out) {
    const int tid  = threadIdx.x;
    const int wave = tid >> 6;
    const int lane = tid & 63;
    const int fr   = lane & 15;
    const int fq   = lane >> 4;
    const int m0   = blockIdx.x * 64;

    int row = m0 + wave * 16 + fr;
    if (row > NN - 1) row = NN - 1;             // tail clamp (epilogue guards)
    const size_t arow = (size_t)row * D;

    f32x4 acc[8];
#pragma unroll
    for (int j = 0; j < 8; ++j) acc[j] = (f32x4){0.f, 0.f, 0.f, 0.f};

    for (int p = 0; p <= NR; ++p) {
        const u16* Ap = ((p == 0) ? xb : sums + (size_t)(p - 1) * NN * D) + arow;
        const u16* Bp = bpk + (size_t)p * 16 * 128 * 8;
#pragma unroll
        for (int kk = 0; kk < 4; ++kk) {
            const int ch = kk * 4 + fq;
            s16x8 af = *(const s16x8*)(Ap + ch * 8);
#pragma unroll
            for (int nt = 0; nt < 8; ++nt) {
                s16x8 bf = *(const s16x8*)(Bp + ((size_t)ch * 128 + nt * 16 + fr) * 8);
                acc[nt] = __builtin_amdgcn_mfma_f32_16x16x32_bf16(af, bf, acc[nt], 0, 0, 0);
            }
        }
    }

    // epilogue: C/D layout col=lane&15, row=(lane>>4)*4+reg
    const int rq = fq * 4;
#pragma unroll
    for (int nt = 0; nt < 8; ++nt) {
        int col = nt * 16 + fr;
        float bv = bias[col];
#pragma unroll
        for (int reg = 0; reg < 4; ++reg) {
            int n = m0 + 16 * wave + rq + reg;
            if (n < NN) {
                float v = acc[nt][reg] + bv;
                out[(size_t)n * D + col] = fmaxf(v, 0.0f);
            }
        }
    }
}

extern "C" void kernel_launch(void* const* d_in, const int* in_sizes, int n_in,
                              void* d_out, int out_size, void* d_ws, size_t ws_size,
                              hipStream_t stream) {
    const float* x      = (const float*)d_in[0];
    const int*   ei     = (const int*)d_in[1];
    const int*   et     = (const int*)d_in[2];
    const float* weight = (const float*)d_in[3];
    const float* root   = (const float*)d_in[4];
    const float* bias   = (const float*)d_in[5];
    float* out = (float*)d_out;
    const int* srcv = ei;
    const int* dstv = ei + NE;

    // ws: ints [cnt2 NSEG][cur2 NSEG][offs2 NSEG+1][bsums 512][ebin NE],
    // then u16 [xb NN*D][sums NR*NN*D][bpk (NR+1)*D*D]   (~118 MB)
    int* cnt2  = (int*)d_ws;
    int* cur2  = cnt2 + NSEG;
    int* offs2 = cur2 + NSEG;
    int* bsums = offs2 + NSEG + 1;
    int* ebin  = bsums + 512;
    size_t fixed_b  = ((char*)(ebin + NE) - (char*)d_ws);
    size_t fixed_al = (fixed_b + 255) & ~(size_t)255;
    u16* xb   = (u16*)((char*)d_ws + fixed_al);
    u16* sums = xb + (size_t)NN * D;
    u16* bpk  = sums + (size_t)NR * NN * D;

    hipMemsetAsync(cnt2, 0, NSEG * sizeof(int), stream);

    const int PREP = NN * D / 4 + (NR + 1) * D * D + NE;
    prep_all<<<(PREP + 255) / 256, 256, 0, stream>>>(x, weight, root, dstv, et,
                                                     xb, bpk, cnt2);

    scan1<<<NBLK2, 256, 0, stream>>>(cnt2, offs2, bsums);
    scan2<<<1, 512, 0, stream>>>(bsums);
    scan3<<<(NSEG + 256) / 256, 256, 0, stream>>>(offs2, cur2, bsums);
    fill_bins<<<(NE + 255) / 256, 256, 0, stream>>>(srcv, dstv, et, cur2, ebin);

    aggregate_kernel<<<(NN + 1) / 2, 128, 0, stream>>>((const u32*)xb, offs2, ebin,
                                                       (u32*)sums);

    mfma_gemm<<<(NN + 63) / 64, 256, 0, stream>>>(xb, sums, bpk, bias, out);
}

// Round 12
// 222.028 us; speedup vs baseline: 1.2333x; 1.0921x over previous
//
#include <hip/hip_runtime.h>

constexpr int NN = 50000;   // nodes
constexpr int NE = 600000;  // edges
constexpr int D  = 128;     // features
constexpr int NR = 8;       // relations
constexpr int NSEG = NN * NR;        // 400000 (dst, rel) segments

constexpr int SCAN_ELEMS = 1024;
constexpr int NBLK2 = (NSEG + SCAN_ELEMS - 1) / SCAN_ELEMS;   // 391

typedef unsigned int   u32;
typedef unsigned short u16;
typedef float  f32x4 __attribute__((ext_vector_type(4)));
typedef short  s16x8 __attribute__((ext_vector_type(8)));

__device__ __forceinline__ u16 f2bf(float f) {
    u32 u = __float_as_uint(f);
    u32 r = (u + 0x7fffu + ((u >> 16) & 1u)) >> 16;   // RNE
    return (u16)r;
}

__device__ __forceinline__ void async_cp16(const void* g, void* l) {
    __builtin_amdgcn_global_load_lds(
        (const __attribute__((address_space(1))) u32*)g,
        (__attribute__((address_space(3))) u32*)l, 16, 0, 0);
}

// ---------------- fused prep: count + convert_x + pack W -----------------
// bpk layout (MFMA B-fragment order): PLANE 0 = root, plane r+1 = weight[r]
// (matches the GEMM's A-plane convention: plane 0 = x, plane p = mean[p-1]).
// Within a plane: k-chunk ch = k>>3 (16 per plane), col c: the 16B chunk at
// ((plane*16+ch)*128 + c)*8 + (k&7).
__global__ __launch_bounds__(256) void prep_all(const float* __restrict__ x,
                                                const float* __restrict__ weight,
                                                const float* __restrict__ root,
                                                const int* __restrict__ dst,
                                                const int* __restrict__ et,
                                                u16* __restrict__ xb,
                                                u16* __restrict__ bpk,
                                                int* __restrict__ cnt2) {
    const int NX4 = NN * D / 4;                 // 1.6M
    const int NW  = (NR + 1) * D * D;           // 147456
    int gid = blockIdx.x * 256 + threadIdx.x;
    if (gid < NX4) {
        int i = gid * 4;
        float4 v = *(const float4*)(x + i);
        ushort4 o;
        o.x = f2bf(v.x); o.y = f2bf(v.y); o.z = f2bf(v.z); o.w = f2bf(v.w);
        *(ushort4*)(xb + i) = o;
        return;
    }
    int g = gid - NX4;
    if (g < NW) {
        int p = g >> 14;          // source plane 0..8 (0..7 = weight, 8 = root)
        int idx = g & 16383;      // c*128 + k
        int c = idx >> 7, k = idx & 127;
        float v  = (p < NR) ? weight[(size_t)p * D * D + k * D + c] : root[k * D + c];
        int   dp = (p < NR) ? (p + 1) : 0;       // dest plane: root first
        bpk[(((size_t)dp * 16 + (k >> 3)) * 128 + c) * 8 + (k & 7)] = f2bf(v);
        return;
    }
    int e = g - NW;
    if (e < NE) atomicAdd(&cnt2[dst[e] * NR + et[e]], 1);
}

// ---------------- scans: exclusive scan of cnt2 -> offs2 -----------------
__global__ __launch_bounds__(256) void scan1(const int* __restrict__ cnt,
                                             int* __restrict__ offs,
                                             int* __restrict__ bsums) {
    __shared__ int lds[256];
    int t = threadIdx.x;
    int base = blockIdx.x * SCAN_ELEMS + t * 4;
    int v0 = (base + 0 < NSEG) ? cnt[base + 0] : 0;
    int v1 = (base + 1 < NSEG) ? cnt[base + 1] : 0;
    int v2 = (base + 2 < NSEG) ? cnt[base + 2] : 0;
    int v3 = (base + 3 < NSEG) ? cnt[base + 3] : 0;
    int s = v0 + v1 + v2 + v3;
    lds[t] = s;
    __syncthreads();
    int val = s;
    for (int off = 1; off < 256; off <<= 1) {
        int tmp = (t >= off) ? lds[t - off] : 0;
        __syncthreads();
        val += tmp;
        lds[t] = val;
        __syncthreads();
    }
    int ex = val - s;
    if (base + 0 < NSEG) offs[base + 0] = ex;
    if (base + 1 < NSEG) offs[base + 1] = ex + v0;
    if (base + 2 < NSEG) offs[base + 2] = ex + v0 + v1;
    if (base + 3 < NSEG) offs[base + 3] = ex + v0 + v1 + v2;
    if (t == 255) bsums[blockIdx.x] = val;
}

__global__ __launch_bounds__(512) void scan2(int* __restrict__ bsums) {
    __shared__ int lds[512];
    int t = threadIdx.x;
    int v = (t < NBLK2) ? bsums[t] : 0;
    lds[t] = v;
    __syncthreads();
    int val = v;
    for (int off = 1; off < 512; off <<= 1) {
        int tmp = (t >= off) ? lds[t - off] : 0;
        __syncthreads();
        val += tmp;
        lds[t] = val;
        __syncthreads();
    }
    if (t < NBLK2) bsums[t] = val - v;
}

__global__ __launch_bounds__(256) void scan3(int* __restrict__ offs,
                                             int* __restrict__ cur,
                                             const int* __restrict__ bsums) {
    int i = blockIdx.x * 256 + threadIdx.x;
    if (i < NSEG) {
        int v = offs[i] + bsums[i >> 10];
        offs[i] = v;
        cur[i]  = v;
    }
    if (i == 0) offs[NSEG] = NE;
}

// ---------------- bin edges by (dst, rel) --------------------------------
__global__ __launch_bounds__(256) void fill_bins(const int* __restrict__ src,
                                                 const int* __restrict__ dst,
                                                 const int* __restrict__ et,
                                                 int* __restrict__ cur,
                                                 int* __restrict__ ebin) {
    int e = blockIdx.x * 256 + threadIdx.x;
    if (e >= NE) return;
    int r = et[e];
    int idx = atomicAdd(&cur[dst[e] * NR + r], 1);
    ebin[idx] = (r << 16) | src[e];   // src < 50000 < 2^16
}

// ---------------- aggregation: relation-sorted, boundary-flush -----------
__global__ __launch_bounds__(128) void aggregate_kernel(const u32* __restrict__ xw,
                                                        const int* __restrict__ offs2,
                                                        const int* __restrict__ ebin,
                                                        u32* __restrict__ sw) {
    const int lane = threadIdx.x & 63;
    const int n = blockIdx.x * 2 + (threadIdx.x >> 6);
    if (n >= NN) return;
    const int beg = __builtin_amdgcn_readfirstlane(offs2[n * NR]);
    const int c   = __builtin_amdgcn_readfirstlane(offs2[n * NR + NR]) - beg;

    float a0 = 0.f, a1 = 0.f;
    int r_cur = 0, cnt_cur = 0;

    int q0 = 0, q1 = 0, q2 = 0, q3 = 0, q4 = 0, q5 = 0, q6 = 0, q7 = 0;
    u32 v0 = 0, v1 = 0, v2 = 0, v3 = 0, v4 = 0, v5 = 0, v6 = 0, v7 = 0;

#define REFILL(Q, V, IDX)                                                   \
    if ((IDX) < c) {                                                        \
        Q = __builtin_amdgcn_readfirstlane(ebin[beg + (IDX)]);              \
        V = xw[(size_t)((u32)Q & 0xffffu) * 64 + lane];                     \
    }
#define FLUSH()                                                             \
    {                                                                       \
        float inv_ = 1.0f / (float)(cnt_cur > 0 ? cnt_cur : 1);             \
        u32 lo16_ = f2bf(a0 * inv_);                                        \
        u32 hi16_ = f2bf(a1 * inv_);                                        \
        sw[((size_t)r_cur * NN + n) * 64 + lane] = lo16_ | (hi16_ << 16);   \
        a0 = 0.f; a1 = 0.f; cnt_cur = 0; ++r_cur;                           \
    }
#define CONSUME(Q, V)                                                       \
    {                                                                       \
        int rj_ = (int)((u32)(Q) >> 16);                                    \
        while (r_cur < rj_) FLUSH()                                         \
        a0 += __uint_as_float((V) << 16);                                   \
        a1 += __uint_as_float((V) & 0xffff0000u);                           \
        ++cnt_cur;                                                          \
    }

    REFILL(q0, v0, 0) REFILL(q1, v1, 1) REFILL(q2, v2, 2) REFILL(q3, v3, 3)
    REFILL(q4, v4, 4) REFILL(q5, v5, 5) REFILL(q6, v6, 6) REFILL(q7, v7, 7)

    int e = 0;
    for (; e + 8 <= c; e += 8) {
        CONSUME(q0, v0) REFILL(q0, v0, e + 8)
        CONSUME(q1, v1) REFILL(q1, v1, e + 9)
        CONSUME(q2, v2) REFILL(q2, v2, e + 10)
        CONSUME(q3, v3) REFILL(q3, v3, e + 11)
        CONSUME(q4, v4) REFILL(q4, v4, e + 12)
        CONSUME(q5, v5) REFILL(q5, v5, e + 13)
        CONSUME(q6, v6) REFILL(q6, v6, e + 14)
        CONSUME(q7, v7) REFILL(q7, v7, e + 15)
    }
    if (e + 0 < c) CONSUME(q0, v0)
    if (e + 1 < c) CONSUME(q1, v1)
    if (e + 2 < c) CONSUME(q2, v2)
    if (e + 3 < c) CONSUME(q3, v3)
    if (e + 4 < c) CONSUME(q4, v4)
    if (e + 5 < c) CONSUME(q5, v5)
    if (e + 6 < c) CONSUME(q6, v6)
    if (e + 7 < c) CONSUME(q7, v7)

    while (r_cur < NR) FLUSH()
#undef REFILL
#undef FLUSH
#undef CONSUME
}

// ---------------- MFMA GEMM: per-plane B staging, direct-load A ----------
// out[n][c] = relu( Σ_k A[n][k] * B[k][c] + bias[c] ), K = 1152.
// BM=64, BN=128, 4 waves x 16 rows. Per plane (9 total): stage the 32KB
// B-plane into LDS in fragment order (8 global_load_lds dwordx4 / thread),
// direct-load this lane's 4 A-fragments (64B, issued before the barrier so
// they share the vmcnt drain), then 32 MFMAs. 18 barriers total vs R8's 72;
// ds_read bank distribution is exactly uniform (8 words/bank per b128).
__global__ __launch_bounds__(256) void mfma_gemm(const u16* __restrict__ xb,
                                                 const u16* __restrict__ sums,
                                                 const u16* __restrict__ bpk,
                                                 const float* __restrict__ bias,
                                                 float* __restrict__ out) {
    __shared__ u16 Bs[16 * 128 * 8];   // 32 KB, fragment order (ch*128+col)*8

    const int tid  = threadIdx.x;
    const int wave = tid >> 6;
    const int lane = tid & 63;
    const int fr   = lane & 15;
    const int fq   = lane >> 4;
    const int m0   = blockIdx.x * 64;

    int row = m0 + wave * 16 + fr;
    if (row > NN - 1) row = NN - 1;             // tail clamp (epilogue guards)
    const size_t arow = (size_t)row * D;

    f32x4 acc[8];
#pragma unroll
    for (int j = 0; j < 8; ++j) acc[j] = (f32x4){0.f, 0.f, 0.f, 0.f};

    for (int p = 0; p <= NR; ++p) {
        const u16* Ap = ((p == 0) ? xb : sums + (size_t)(p - 1) * NN * D) + arow;
        const u16* Bp = bpk + (size_t)p * 16 * 128 * 8;

        __syncthreads();   // prev plane's ds_reads done before overwrite
#pragma unroll
        for (int j = 0; j < 8; ++j)
            async_cp16(Bp + (size_t)(j * 256 + tid) * 8,
                       (char*)Bs + (size_t)(j * 256 + wave * 64) * 16);

        s16x8 af[4];       // A fragments: issued now, drained by the barrier
#pragma unroll
        for (int kk = 0; kk < 4; ++kk)
            af[kk] = *(const s16x8*)(Ap + (kk * 4 + fq) * 8);

        __syncthreads();   // vmcnt drained: Bs (and af) ready

#pragma unroll
        for (int kk = 0; kk < 4; ++kk) {
            const int ch = kk * 4 + fq;
#pragma unroll
            for (int nt = 0; nt < 8; ++nt) {
                s16x8 bf = *(const s16x8*)&Bs[((size_t)ch * 128 + nt * 16 + fr) * 8];
                acc[nt] = __builtin_amdgcn_mfma_f32_16x16x32_bf16(af[kk], bf, acc[nt], 0, 0, 0);
            }
        }
    }

    // epilogue: C/D layout col=lane&15, row=(lane>>4)*4+reg
    const int rq = fq * 4;
#pragma unroll
    for (int nt = 0; nt < 8; ++nt) {
        int col = nt * 16 + fr;
        float bv = bias[col];
#pragma unroll
        for (int reg = 0; reg < 4; ++reg) {
            int n = m0 + 16 * wave + rq + reg;
            if (n < NN) {
                float v = acc[nt][reg] + bv;
                out[(size_t)n * D + col] = fmaxf(v, 0.0f);
            }
        }
    }
}

extern "C" void kernel_launch(void* const* d_in, const int* in_sizes, int n_in,
                              void* d_out, int out_size, void* d_ws, size_t ws_size,
                              hipStream_t stream) {
    const float* x      = (const float*)d_in[0];
    const int*   ei     = (const int*)d_in[1];
    const int*   et     = (const int*)d_in[2];
    const float* weight = (const float*)d_in[3];
    const float* root   = (const float*)d_in[4];
    const float* bias   = (const float*)d_in[5];
    float* out = (float*)d_out;
    const int* srcv = ei;
    const int* dstv = ei + NE;

    // ws: ints [cnt2 NSEG][cur2 NSEG][offs2 NSEG+1][bsums 512][ebin NE],
    // then u16 [xb NN*D][sums NR*NN*D][bpk (NR+1)*D*D]   (~118 MB)
    int* cnt2  = (int*)d_ws;
    int* cur2  = cnt2 + NSEG;
    int* offs2 = cur2 + NSEG;
    int* bsums = offs2 + NSEG + 1;
    int* ebin  = bsums + 512;
    size_t fixed_b  = ((char*)(ebin + NE) - (char*)d_ws);
    size_t fixed_al = (fixed_b + 255) & ~(size_t)255;
    u16* xb   = (u16*)((char*)d_ws + fixed_al);
    u16* sums = xb + (size_t)NN * D;
    u16* bpk  = sums + (size_t)NR * NN * D;

    hipMemsetAsync(cnt2, 0, NSEG * sizeof(int), stream);

    const int PREP = NN * D / 4 + (NR + 1) * D * D + NE;
    prep_all<<<(PREP + 255) / 256, 256, 0, stream>>>(x, weight, root, dstv, et,
                                                     xb, bpk, cnt2);

    scan1<<<NBLK2, 256, 0, stream>>>(cnt2, offs2, bsums);
    scan2<<<1, 512, 0, stream>>>(bsums);
    scan3<<<(NSEG + 256) / 256, 256, 0, stream>>>(offs2, cur2, bsums);
    fill_bins<<<(NE + 255) / 256, 256, 0, stream>>>(srcv, dstv, et, cur2, ebin);

    aggregate_kernel<<<(NN + 1) / 2, 128, 0, stream>>>((const u32*)xb, offs2, ebin,
                                                       (u32*)sums);

    mfma_gemm<<<(NN + 63) / 64, 256, 0, stream>>>(xb, sums, bpk, bias, out);
}